// Round 12
// baseline (898.562 us; speedup 1.0000x reference)
//
#include <hip/hip_runtime.h>
#include <hip/hip_fp16.h>
#include <math.h>

#define NUSERS 100000
#define NITEMS 50000
#define BATCH  64
#define ORDER  8
#define BSHIFT 9                                   // 512 rows per bucket
#define BROWS  (1 << BSHIFT)
#define NBUCKU ((NUSERS + BROWS - 1) >> BSHIFT)    // 196
#define NBUCKI ((NITEMS + BROWS - 1) >> BSHIFT)    // 98
#define S1_BLOCKS 512
#define NREP 4

// ---------------------------------------------------------------------------
// R6: scaled-state tau = di_is(.)t (vals[] never read). R8/R9: bucket-binned
// CSR build. R10/R11: fp16 y + fp16 tau gather copies, replicated-LDS hist.
// R12: (1) obuf deferred -- all 9 fp16 tau_k kept (they were written anyway
//      for the user gather); final transpose computes sum(c_k tau_kH).
//      Removes 25.6MB fp32 RMW per item step.
//      (2) packed __hadd2 group accumulation (halves gather VALU).
//      (3) 4 rows/wave in both SpMMs -> 16 gathers in flight.
// ---------------------------------------------------------------------------

struct __align__(8) Half4 { __half2 a, b; };
struct Coeffs { float v[ORDER + 1]; };

__device__ __forceinline__ void acc_h4(float4& acc, const Half4 h) {
    float2 f0 = __half22float2(h.a);
    float2 f1 = __half22float2(h.b);
    acc.x += f0.x; acc.y += f0.y; acc.z += f1.x; acc.w += f1.y;
}

// packed group-of-4 accumulate: fp16 pair adds, one fp32 convert per group
__device__ __forceinline__ void acc_pk(float4& acc, Half4 v0, Half4 v1,
                                       Half4 v2, Half4 v3) {
    __half2 sa = __hadd2(__hadd2(v0.a, v1.a), __hadd2(v2.a, v3.a));
    __half2 sb = __hadd2(__hadd2(v0.b, v1.b), __hadd2(v2.b, v3.b));
    float2 fa = __half22float2(sa);
    float2 fb = __half22float2(sb);
    acc.x += fa.x; acc.y += fa.y; acc.z += fb.x; acc.w += fb.y;
}

__device__ __forceinline__ Half4 to_h4(float x, float y, float z, float w) {
    Half4 h;
    h.a = __floats2half2_rn(x, y);
    h.b = __floats2half2_rn(z, w);
    return h;
}

// transpose + prescale: tau0 fp32 AND fp16 copy (tauHall slot 0)
__global__ void transpose_scale_k(const float* __restrict__ in,   // [BATCH][NITEMS]
                                  const float* __restrict__ dis,
                                  float* __restrict__ out,        // fp32
                                  __half* __restrict__ outH) {    // fp16
    __shared__ float tile[32][33];
    const int cb = blockIdx.x * 32;   // item base
    const int rb = blockIdx.y * 32;   // batch base
    for (int i = threadIdx.y; i < 32; i += 8) {
        int r = rb + i, c = cb + threadIdx.x;
        if (r < BATCH && c < NITEMS) tile[i][threadIdx.x] = in[(size_t)r * NITEMS + c];
    }
    __syncthreads();
    for (int i = threadIdx.y; i < 32; i += 8) {
        int c = cb + i, r = rb + threadIdx.x;   // c = item, r = batch
        if (c < NITEMS && r < BATCH) {
            float v = dis[c] * tile[threadIdx.x][i];
            out[(size_t)c * BATCH + r] = v;
            outH[(size_t)c * BATCH + r] = __float2half(v);
        }
    }
}

// final: out[b][i] = sqrt(di)*sum_k c_k tauH_k[i][b], isolated -> csum*signal
__global__ void transpose_out_k(const __half* __restrict__ tauHall,
                                const float* __restrict__ signal,
                                const int* __restrict__ iptr, float csum, Coeffs cf,
                                float* __restrict__ out) {
    __shared__ float tile[32][33];
    const int cb = blockIdx.x * 32;   // batch base
    const int rb = blockIdx.y * 32;   // item base
    const size_t NB = (size_t)NITEMS * BATCH;
    for (int i = threadIdx.y; i < 32; i += 8) {
        int r = rb + i, c = cb + threadIdx.x;
        if (r < NITEMS && c < BATCH) {
            size_t base = (size_t)r * BATCH + c;
            float s = 0.f;
            #pragma unroll
            for (int k = 0; k <= ORDER; ++k)
                s += cf.v[k] * __half2float(tauHall[(size_t)k * NB + base]);
            tile[i][threadIdx.x] = s;
        }
    }
    __syncthreads();
    for (int i = threadIdx.y; i < 32; i += 8) {
        int c = cb + i, r = rb + threadIdx.x;   // c = batch, r = item
        if (c < BATCH && r < NITEMS) {
            int d = iptr[r + 1] - iptr[r];
            float v = (d > 0) ? sqrtf((float)d) * tile[threadIdx.x][i]
                              : csum * signal[(size_t)c * NITEMS + r];
            out[(size_t)c * NITEMS + r] = v;
        }
    }
}

// ---------------------------------------------------------------------------
// CSR build (unchanged from R11)
// ---------------------------------------------------------------------------
__global__ void bucket_hist(const int* __restrict__ row, const int* __restrict__ col,
                            int* __restrict__ bcntU, int* __restrict__ bcntI, int nnz) {
    __shared__ int cU[NREP][NBUCKU];
    __shared__ int cI[NREP][NBUCKI];
    const int chunk = (nnz + S1_BLOCKS - 1) / S1_BLOCKS;
    const int b0 = blockIdx.x * chunk;
    const int e0 = min(b0 + chunk, nnz);
    const int sw = threadIdx.x >> 6;
    for (int t = threadIdx.x; t < NREP * NBUCKU; t += blockDim.x) (&cU[0][0])[t] = 0;
    for (int t = threadIdx.x; t < NREP * NBUCKI; t += blockDim.x) (&cI[0][0])[t] = 0;
    __syncthreads();
    for (int i = b0 + threadIdx.x; i < e0; i += blockDim.x) {
        atomicAdd(&cU[sw][row[i] >> BSHIFT], 1);
        atomicAdd(&cI[sw][col[i] >> BSHIFT], 1);
    }
    __syncthreads();
    for (int t = threadIdx.x; t < NBUCKU; t += blockDim.x) {
        int s = cU[0][t] + cU[1][t] + cU[2][t] + cU[3][t];
        if (s > 0) atomicAdd(&bcntU[t], s);
    }
    for (int t = threadIdx.x; t < NBUCKI; t += blockDim.x) {
        int s = cI[0][t] + cI[1][t] + cI[2][t] + cI[3][t];
        if (s > 0) atomicAdd(&bcntI[t], s);
    }
}

__global__ void bucket_scan(const int* __restrict__ bcntU, const int* __restrict__ bcntI,
                            int* __restrict__ bofsU, int* __restrict__ bofsI,
                            int* __restrict__ bcurU, int* __restrict__ bcurI) {
    __shared__ int ls[256];
    const int t = threadIdx.x;
    int v = (t < NBUCKU) ? bcntU[t] : 0;
    ls[t] = v;
    __syncthreads();
    for (int off = 1; off < 256; off <<= 1) {
        int u = (t >= off) ? ls[t - off] : 0;
        __syncthreads();
        ls[t] += u;
        __syncthreads();
    }
    if (t < NBUCKU) {
        int excl = ls[t] - v;
        bofsU[t] = excl;
        bcurU[t] = excl;
    }
    if (t == NBUCKU - 1) bofsU[NBUCKU] = ls[t];
    __syncthreads();
    v = (t < NBUCKI) ? bcntI[t] : 0;
    ls[t] = v;
    __syncthreads();
    for (int off = 1; off < 256; off <<= 1) {
        int u = (t >= off) ? ls[t - off] : 0;
        __syncthreads();
        ls[t] += u;
        __syncthreads();
    }
    if (t < NBUCKI) {
        int excl = ls[t] - v;
        bofsI[t] = excl;
        bcurI[t] = excl;
    }
    __syncthreads();
    if (t == NBUCKI - 1) bofsI[NBUCKI] = ls[t];
}

__global__ void scatter1(const int* __restrict__ row, const int* __restrict__ col,
                         int* __restrict__ bcurU, int* __restrict__ bcurI,
                         int* __restrict__ stU, int* __restrict__ stI, int nnz) {
    __shared__ int cU[NREP][NBUCKU];
    __shared__ int cI[NREP][NBUCKI];
    const int chunk = (nnz + S1_BLOCKS - 1) / S1_BLOCKS;
    const int b0 = blockIdx.x * chunk;
    const int e0 = min(b0 + chunk, nnz);
    const int sw = threadIdx.x >> 6;
    for (int t = threadIdx.x; t < NREP * NBUCKU; t += blockDim.x) (&cU[0][0])[t] = 0;
    for (int t = threadIdx.x; t < NREP * NBUCKI; t += blockDim.x) (&cI[0][0])[t] = 0;
    __syncthreads();
    for (int i = b0 + threadIdx.x; i < e0; i += blockDim.x) {
        atomicAdd(&cU[sw][row[i] >> BSHIFT], 1);
        atomicAdd(&cI[sw][col[i] >> BSHIFT], 1);
    }
    __syncthreads();
    for (int t = threadIdx.x; t < NBUCKU; t += blockDim.x) {
        int c0 = cU[0][t], c1 = cU[1][t], c2 = cU[2][t], c3 = cU[3][t];
        int tot = c0 + c1 + c2 + c3;
        int base = (tot > 0) ? atomicAdd(&bcurU[t], tot) : 0;
        cU[0][t] = base;
        cU[1][t] = base + c0;
        cU[2][t] = base + c0 + c1;
        cU[3][t] = base + c0 + c1 + c2;
    }
    for (int t = threadIdx.x; t < NBUCKI; t += blockDim.x) {
        int c0 = cI[0][t], c1 = cI[1][t], c2 = cI[2][t], c3 = cI[3][t];
        int tot = c0 + c1 + c2 + c3;
        int base = (tot > 0) ? atomicAdd(&bcurI[t], tot) : 0;
        cI[0][t] = base;
        cI[1][t] = base + c0;
        cI[2][t] = base + c0 + c1;
        cI[3][t] = base + c0 + c1 + c2;
    }
    __syncthreads();
    for (int i = b0 + threadIdx.x; i < e0; i += blockDim.x) {
        int r = row[i], c = col[i];
        int pu = atomicAdd(&cU[sw][r >> BSHIFT], 1);
        stU[pu] = ((r & (BROWS - 1)) << 17) | c;
        int pi = atomicAdd(&cI[sw][c >> BSHIFT], 1);
        stI[pi] = ((c & (BROWS - 1)) << 17) | r;
    }
}

__global__ void scatter2(const int* __restrict__ bofs, const int* __restrict__ st,
                         int* __restrict__ ptr, int* __restrict__ outIdx, int nrows) {
    __shared__ int deg[BROWS];
    __shared__ int ps[256];
    __shared__ int cur[BROWS];
    const int rbase = blockIdx.x << BSHIFT;
    const int nr = min(BROWS, nrows - rbase);
    const int lo = bofs[blockIdx.x];
    const int hi = bofs[blockIdx.x + 1];
    const int t = threadIdx.x;
    deg[2 * t] = 0;
    deg[2 * t + 1] = 0;
    __syncthreads();
    for (int j = lo + t; j < hi; j += 256)
        atomicAdd(&deg[st[j] >> 17], 1);
    __syncthreads();
    int a = deg[2 * t];
    int b = deg[2 * t + 1];
    ps[t] = a + b;
    __syncthreads();
    for (int off = 1; off < 256; off <<= 1) {
        int u = (t >= off) ? ps[t - off] : 0;
        __syncthreads();
        ps[t] += u;
        __syncthreads();
    }
    int excl = (t > 0) ? ps[t - 1] : 0;
    int p0 = lo + excl;
    int p1 = p0 + a;
    cur[2 * t] = p0;
    cur[2 * t + 1] = p1;
    if (2 * t < nr)     ptr[rbase + 2 * t] = p0;
    if (2 * t + 1 < nr) ptr[rbase + 2 * t + 1] = p1;
    if (t == 0 && rbase + BROWS >= nrows) ptr[nrows] = hi;
    __syncthreads();
    for (int j = lo + t; j < hi; j += 256) {
        int v = st[j];
        int p = atomicAdd(&cur[v >> 17], 1);
        outIdx[p] = v & 0x1FFFF;
    }
}

__global__ void scale_k(const int* __restrict__ uptr, const int* __restrict__ iptr,
                        float* __restrict__ du2, float* __restrict__ di2,
                        float* __restrict__ dis) {
    int t = blockIdx.x * blockDim.x + threadIdx.x;
    if (t < NUSERS) {
        int d = uptr[t + 1] - uptr[t];
        du2[t] = (d > 0) ? 1.0f / (float)d : 0.0f;
    }
    if (t < NITEMS) {
        int d = iptr[t + 1] - iptr[t];
        di2[t] = (d > 0) ? 1.0f / (float)d : 0.0f;
        dis[t] = (d > 0) ? 1.0f / sqrtf((float)d) : 0.0f;
    }
}

// ---------------------------------------------------------------------------
// 4-row fp16 gather core: 16 independent gathers in flight per macro-iter.
// Row bounds are wave-uniform -> scalar branches, no divergence cost.
// ---------------------------------------------------------------------------
__device__ __forceinline__ void gather4_h(const int* __restrict__ ptr,
                                          const int* __restrict__ idx,
                                          const Half4* __restrict__ x,
                                          const int* r, int sub, int bh,
                                          float4* a) {
    int b[4], e[4], n[4], j[4];
    int nmax = 0;
    #pragma unroll
    for (int q = 0; q < 4; ++q) {
        b[q] = ptr[r[q]];
        e[q] = ptr[r[q] + 1];
        n[q] = (e[q] - b[q]) >> 4;
        j[q] = b[q] + (sub << 2);
        nmax = max(nmax, n[q]);
    }
    for (int it = 0; it < nmax; ++it) {
        #pragma unroll
        for (int q = 0; q < 4; ++q) {
            if (it < n[q]) {
                int i0 = idx[j[q]], i1 = idx[j[q] + 1];
                int i2 = idx[j[q] + 2], i3 = idx[j[q] + 3];
                Half4 v0 = x[(size_t)i0 * 16 + bh];
                Half4 v1 = x[(size_t)i1 * 16 + bh];
                Half4 v2 = x[(size_t)i2 * 16 + bh];
                Half4 v3 = x[(size_t)i3 * 16 + bh];
                acc_pk(a[q], v0, v1, v2, v3);
                j[q] += 16;
            }
        }
    }
    #pragma unroll
    for (int q = 0; q < 4; ++q)
        for (int jj = b[q] + (n[q] << 4) + sub; jj < e[q]; jj += 4)
            acc_h4(a[q], x[(size_t)idx[jj] * 16 + bh]);
    #pragma unroll
    for (int q = 0; q < 4; ++q) {
        a[q].x += __shfl_xor(a[q].x, 16); a[q].y += __shfl_xor(a[q].y, 16);
        a[q].z += __shfl_xor(a[q].z, 16); a[q].w += __shfl_xor(a[q].w, 16);
        a[q].x += __shfl_xor(a[q].x, 32); a[q].y += __shfl_xor(a[q].y, 32);
        a[q].z += __shfl_xor(a[q].z, 32); a[q].w += __shfl_xor(a[q].w, 32);
    }
}

// user side: y[u] = du2[u] * sum tauH[col]
__global__ void spmm_user(const int* __restrict__ ptr, const int* __restrict__ idx,
                          const float* __restrict__ du2,
                          const Half4* __restrict__ tauH, Half4* __restrict__ y) {
    const int lane = threadIdx.x & 63;
    const int w = (blockIdx.x * blockDim.x + threadIdx.x) >> 6;
    const int H = NUSERS / 4;
    if (w >= H) return;
    int r[4] = {w, w + H, w + 2 * H, w + 3 * H};
    const int sub = lane >> 4;
    const int bh  = lane & 15;
    float4 a[4] = {{0,0,0,0},{0,0,0,0},{0,0,0,0},{0,0,0,0}};
    gather4_h(ptr, idx, tauH, r, sub, bh, a);
    if (sub == 0) {
        #pragma unroll
        for (int q = 0; q < 4; ++q) {
            float s = du2[r[q]];
            y[(size_t)r[q] * 16 + bh] = to_h4(s * a[q].x, s * a[q].y, s * a[q].z, s * a[q].w);
        }
    }
}

// item, first step: tau1 = tau0 - 2*di2*z ; write fp32 + fp16 (no obuf)
__global__ void spmm_item_first(const int* __restrict__ ptr, const int* __restrict__ idx,
                                const float* __restrict__ di2, const Half4* __restrict__ y,
                                const float* __restrict__ tau0, float* __restrict__ tau1,
                                Half4* __restrict__ tauH1) {
    const int lane = threadIdx.x & 63;
    const int w = (blockIdx.x * blockDim.x + threadIdx.x) >> 6;
    const int H = NITEMS / 4;
    if (w >= H) return;
    int r[4] = {w, w + H, w + 2 * H, w + 3 * H};
    const int sub = lane >> 4;
    const int bh  = lane & 15;
    float4 a[4] = {{0,0,0,0},{0,0,0,0},{0,0,0,0},{0,0,0,0}};
    gather4_h(ptr, idx, y, r, sub, bh, a);
    if (sub == 0) {
        #pragma unroll
        for (int q = 0; q < 4; ++q) {
            float s2 = 2.0f * di2[r[q]];
            size_t base = (size_t)r[q] * BATCH + (bh << 2);
            float4 t0v = *(const float4*)&tau0[base];
            float4 t;
            t.x = t0v.x - s2 * a[q].x; t.y = t0v.y - s2 * a[q].y;
            t.z = t0v.z - s2 * a[q].z; t.w = t0v.w - s2 * a[q].w;
            *(float4*)&tau1[base] = t;
            tauH1[(size_t)r[q] * 16 + bh] = to_h4(t.x, t.y, t.z, t.w);
        }
    }
}

// item, general step: t2 = 2*t1 - 4*di2*z - t0 ; write fp32 + fp16 (no obuf)
__global__ void spmm_item_k(const int* __restrict__ ptr, const int* __restrict__ idx,
                            const float* __restrict__ di2, const Half4* __restrict__ y,
                            const float* __restrict__ tau1, float* __restrict__ tau0,
                            Half4* __restrict__ tauHk) {
    const int lane = threadIdx.x & 63;
    const int w = (blockIdx.x * blockDim.x + threadIdx.x) >> 6;
    const int H = NITEMS / 4;
    if (w >= H) return;
    int r[4] = {w, w + H, w + 2 * H, w + 3 * H};
    const int sub = lane >> 4;
    const int bh  = lane & 15;
    float4 a[4] = {{0,0,0,0},{0,0,0,0},{0,0,0,0},{0,0,0,0}};
    gather4_h(ptr, idx, y, r, sub, bh, a);
    if (sub == 0) {
        #pragma unroll
        for (int q = 0; q < 4; ++q) {
            float s4 = 4.0f * di2[r[q]];
            size_t base = (size_t)r[q] * BATCH + (bh << 2);
            float4 t1v = *(const float4*)&tau1[base];
            float4 t0v = *(const float4*)&tau0[base];
            float4 t2;
            t2.x = 2.0f * t1v.x - s4 * a[q].x - t0v.x;
            t2.y = 2.0f * t1v.y - s4 * a[q].y - t0v.y;
            t2.z = 2.0f * t1v.z - s4 * a[q].z - t0v.z;
            t2.w = 2.0f * t1v.w - s4 * a[q].w - t0v.w;
            *(float4*)&tau0[base] = t2;
            tauHk[(size_t)r[q] * 16 + bh] = to_h4(t2.x, t2.y, t2.z, t2.w);
        }
    }
}

// ---------------------------------------------------------------------------
// Host-side exact replica of reference cheby_coeffs
// ---------------------------------------------------------------------------
static void cheby_coeffs_host(float* c) {
    const int order = ORDER, flatness = 2;
    const double PI = 3.14159265358979323846;
    double tgt[ORDER + 1], nodes[ORDER + 1];
    for (int x = 0; x <= order; ++x) {
        double xv = cos((double)(order - x) / order * PI);
        xv = nearbyint(xv * 1000.0) / 1000.0;
        double t = (xv < 0.0) ? pow(-xv, (double)flatness) * 0.5 + 0.5
                              : pow(xv, (double)flatness) * (-0.5) + 0.5;
        tgt[x] = nearbyint(t * 1000.0) / 1000.0;
    }
    for (int k = 1; k <= order + 1; ++k)
        nodes[k - 1] = cos((order + 1 + 0.5 - k) / (double)(order + 1) * PI);

    double prev[ORDER + 1], cur[ORDER + 1], nxt[ORDER + 1];
    double sums[ORDER + 1];
    double s0 = 0, s1 = 0;
    for (int i = 0; i <= order; ++i) {
        prev[i] = tgt[i];
        cur[i]  = nodes[i] * tgt[i];
        s0 += prev[i];
        s1 += cur[i];
    }
    sums[0] = s0; sums[1] = s1;
    for (int j = 2; j <= order; ++j) {
        double s = 0;
        for (int i = 0; i <= order; ++i) {
            nxt[i] = nodes[i] * cur[i] * 2.0 - prev[i];
            s += nxt[i];
        }
        sums[j] = s;
        for (int i = 0; i <= order; ++i) { prev[i] = cur[i]; cur[i] = nxt[i]; }
    }
    for (int j = 0; j <= order; ++j)
        c[j] = (float)(sums[j] * (2.0 / (order + 1)));
    c[0] *= 0.5f;
}

extern "C" void kernel_launch(void* const* d_in, const int* in_sizes, int n_in,
                              void* d_out, int out_size, void* d_ws, size_t ws_size,
                              hipStream_t stream) {
    const float* signal = (const float*)d_in[0];   // [BATCH, NITEMS]
    const int*   row    = (const int*)d_in[2];     // [NNZ] -> users
    const int*   col    = (const int*)d_in[3];     // [NNZ] -> items
    const int nnz = in_sizes[1];

    char* wsb = (char*)d_ws;
    size_t off = 0;
    auto carve = [&](size_t nbytes) {
        void* p = wsb + off;
        off += (nbytes + 255) & ~(size_t)255;
        return p;
    };
    const size_t NB = (size_t)NITEMS * BATCH;
    const size_t UB = (size_t)NUSERS * BATCH;
    float*  tauA   = (float*)carve(NB * 4);
    float*  tauB   = (float*)carve(NB * 4);
    __half* tauHall = (__half*)carve((ORDER + 1) * NB * 2);  // 9 x 6.4MB fp16 tau_k
    Half4*  ybuf   = (Half4*)carve(UB * 2);
    int*    uptr   = (int*)carve((NUSERS + 1) * 4);
    int*    iptr   = (int*)carve((NITEMS + 1) * 4);
    int*    bcntU  = (int*)carve(NBUCKU * 4);
    int*    bcntI  = (int*)carve(NBUCKI * 4);
    int*    bofsU  = (int*)carve((NBUCKU + 1) * 4);
    int*    bofsI  = (int*)carve((NBUCKI + 1) * 4);
    int*    bcurU  = (int*)carve(NBUCKU * 4);
    int*    bcurI  = (int*)carve(NBUCKI * 4);
    float*  du2    = (float*)carve(NUSERS * 4);
    float*  di2    = (float*)carve(NITEMS * 4);
    float*  dis    = (float*)carve(NITEMS * 4);
    int*    ucol   = (int*)carve((size_t)nnz * 4);
    int*    irow   = (int*)carve((size_t)nnz * 4);
    // staging aliases tauHall (dead until transpose_scale, which runs after build)
    int*    stU    = (int*)tauHall;
    int*    stI    = (int*)tauHall + nnz;
    (void)ws_size;

    float c[ORDER + 1];
    cheby_coeffs_host(c);
    Coeffs cf;
    float csum = 0.f;
    for (int k = 0; k <= ORDER; ++k) { cf.v[k] = c[k]; csum += c[k]; }

    // ---- bucket-level histogram + scan ----
    hipMemsetAsync(bcntU, 0, (NBUCKU + NBUCKI + 64) * 4, stream);
    bucket_hist<<<S1_BLOCKS, 256, 0, stream>>>(row, col, bcntU, bcntI, nnz);
    bucket_scan<<<1, 256, 0, stream>>>(bcntU, bcntI, bofsU, bofsI, bcurU, bcurI);

    // ---- binned scatter + per-bucket CSR finalize ----
    scatter1<<<S1_BLOCKS, 256, 0, stream>>>(row, col, bcurU, bcurI, stU, stI, nnz);
    scatter2<<<NBUCKU, 256, 0, stream>>>(bofsU, stU, uptr, ucol, NUSERS);
    scatter2<<<NBUCKI, 256, 0, stream>>>(bofsI, stI, iptr, irow, NITEMS);

    // ---- scales ----
    scale_k<<<(NUSERS + 255) / 256, 256, 0, stream>>>(uptr, iptr, du2, di2, dis);

    // ---- tau0 (fp32 + fp16 slot 0) ----
    dim3 tb(32, 8);
    transpose_scale_k<<<dim3((NITEMS + 31) / 32, (BATCH + 31) / 32), tb, 0, stream>>>(
        signal, dis, tauA, tauHall);

    const int ug = ((NUSERS / 4) * 64 + 255) / 256;   // 4 rows per wave
    const int ig = ((NITEMS / 4) * 64 + 255) / 256;

    // ---- k = 1 ----
    spmm_user<<<ug, 256, 0, stream>>>(uptr, ucol, du2, (const Half4*)tauHall, ybuf);
    spmm_item_first<<<ig, 256, 0, stream>>>(iptr, irow, di2, ybuf, tauA, tauB,
                                            (Half4*)(tauHall + NB));

    float* t0 = tauA;
    float* t1 = tauB;
    for (int k = 2; k <= ORDER; ++k) {
        spmm_user<<<ug, 256, 0, stream>>>(uptr, ucol, du2,
                                          (const Half4*)(tauHall + (size_t)(k - 1) * NB), ybuf);
        spmm_item_k<<<ig, 256, 0, stream>>>(iptr, irow, di2, ybuf, t1, t0,
                                            (Half4*)(tauHall + (size_t)k * NB));
        float* tmp = t0; t0 = t1; t1 = tmp;
    }

    // ---- d_out = sqrt(di) * sum_k c_k tauH_k, transposed ----
    transpose_out_k<<<dim3((BATCH + 31) / 32, (NITEMS + 31) / 32), tb, 0, stream>>>(
        tauHall, signal, iptr, csum, cf, (float*)d_out);
}

// Round 13
// 871.837 us; speedup vs baseline: 1.0307x; 1.0307x over previous
//
#include <hip/hip_runtime.h>
#include <hip/hip_fp16.h>
#include <math.h>

#define NUSERS 100000
#define NITEMS 50000
#define BATCH  64
#define ORDER  8
#define BSHIFT 9                                   // 512 rows per bucket
#define BROWS  (1 << BSHIFT)
#define NBUCKU ((NUSERS + BROWS - 1) >> BSHIFT)    // 196
#define NBUCKI ((NITEMS + BROWS - 1) >> BSHIFT)    // 98
#define S1_BLOCKS 512
#define NREP 4

// ---------------------------------------------------------------------------
// R6: scaled-state tau = di_is(.)t (vals[] never read). R8/R9: bucket-binned
// CSR build. R10/R11: fp16 y + fp16 tau gathers. R12: obuf deferred to final
// transpose (9 fp16 tau_k kept), packed __hadd2, 4-row item gather.
// R13: user SpMM back to 2 rows/wave (deg~16: 4-row ran ~1 macro-iter then
// serial tails -- measured 45us vs ~40 at R11); item stays 4-row (deg~32).
// ---------------------------------------------------------------------------

struct __align__(8) Half4 { __half2 a, b; };
struct Coeffs { float v[ORDER + 1]; };

__device__ __forceinline__ void acc_h4(float4& acc, const Half4 h) {
    float2 f0 = __half22float2(h.a);
    float2 f1 = __half22float2(h.b);
    acc.x += f0.x; acc.y += f0.y; acc.z += f1.x; acc.w += f1.y;
}

// packed group-of-4 accumulate: fp16 pair adds, one fp32 convert per group
__device__ __forceinline__ void acc_pk(float4& acc, Half4 v0, Half4 v1,
                                       Half4 v2, Half4 v3) {
    __half2 sa = __hadd2(__hadd2(v0.a, v1.a), __hadd2(v2.a, v3.a));
    __half2 sb = __hadd2(__hadd2(v0.b, v1.b), __hadd2(v2.b, v3.b));
    float2 fa = __half22float2(sa);
    float2 fb = __half22float2(sb);
    acc.x += fa.x; acc.y += fa.y; acc.z += fb.x; acc.w += fb.y;
}

__device__ __forceinline__ Half4 to_h4(float x, float y, float z, float w) {
    Half4 h;
    h.a = __floats2half2_rn(x, y);
    h.b = __floats2half2_rn(z, w);
    return h;
}

// transpose + prescale: tau0 fp32 AND fp16 copy (tauHall slot 0)
__global__ void transpose_scale_k(const float* __restrict__ in,   // [BATCH][NITEMS]
                                  const float* __restrict__ dis,
                                  float* __restrict__ out,        // fp32
                                  __half* __restrict__ outH) {    // fp16
    __shared__ float tile[32][33];
    const int cb = blockIdx.x * 32;   // item base
    const int rb = blockIdx.y * 32;   // batch base
    for (int i = threadIdx.y; i < 32; i += 8) {
        int r = rb + i, c = cb + threadIdx.x;
        if (r < BATCH && c < NITEMS) tile[i][threadIdx.x] = in[(size_t)r * NITEMS + c];
    }
    __syncthreads();
    for (int i = threadIdx.y; i < 32; i += 8) {
        int c = cb + i, r = rb + threadIdx.x;   // c = item, r = batch
        if (c < NITEMS && r < BATCH) {
            float v = dis[c] * tile[threadIdx.x][i];
            out[(size_t)c * BATCH + r] = v;
            outH[(size_t)c * BATCH + r] = __float2half(v);
        }
    }
}

// final: out[b][i] = sqrt(di)*sum_k c_k tauH_k[i][b], isolated -> csum*signal
__global__ void transpose_out_k(const __half* __restrict__ tauHall,
                                const float* __restrict__ signal,
                                const int* __restrict__ iptr, float csum, Coeffs cf,
                                float* __restrict__ out) {
    __shared__ float tile[32][33];
    const int cb = blockIdx.x * 32;   // batch base
    const int rb = blockIdx.y * 32;   // item base
    const size_t NB = (size_t)NITEMS * BATCH;
    for (int i = threadIdx.y; i < 32; i += 8) {
        int r = rb + i, c = cb + threadIdx.x;
        if (r < NITEMS && c < BATCH) {
            size_t base = (size_t)r * BATCH + c;
            float s = 0.f;
            #pragma unroll
            for (int k = 0; k <= ORDER; ++k)
                s += cf.v[k] * __half2float(tauHall[(size_t)k * NB + base]);
            tile[i][threadIdx.x] = s;
        }
    }
    __syncthreads();
    for (int i = threadIdx.y; i < 32; i += 8) {
        int c = cb + i, r = rb + threadIdx.x;   // c = batch, r = item
        if (c < BATCH && r < NITEMS) {
            int d = iptr[r + 1] - iptr[r];
            float v = (d > 0) ? sqrtf((float)d) * tile[threadIdx.x][i]
                              : csum * signal[(size_t)c * NITEMS + r];
            out[(size_t)c * NITEMS + r] = v;
        }
    }
}

// ---------------------------------------------------------------------------
// CSR build (unchanged)
// ---------------------------------------------------------------------------
__global__ void bucket_hist(const int* __restrict__ row, const int* __restrict__ col,
                            int* __restrict__ bcntU, int* __restrict__ bcntI, int nnz) {
    __shared__ int cU[NREP][NBUCKU];
    __shared__ int cI[NREP][NBUCKI];
    const int chunk = (nnz + S1_BLOCKS - 1) / S1_BLOCKS;
    const int b0 = blockIdx.x * chunk;
    const int e0 = min(b0 + chunk, nnz);
    const int sw = threadIdx.x >> 6;
    for (int t = threadIdx.x; t < NREP * NBUCKU; t += blockDim.x) (&cU[0][0])[t] = 0;
    for (int t = threadIdx.x; t < NREP * NBUCKI; t += blockDim.x) (&cI[0][0])[t] = 0;
    __syncthreads();
    for (int i = b0 + threadIdx.x; i < e0; i += blockDim.x) {
        atomicAdd(&cU[sw][row[i] >> BSHIFT], 1);
        atomicAdd(&cI[sw][col[i] >> BSHIFT], 1);
    }
    __syncthreads();
    for (int t = threadIdx.x; t < NBUCKU; t += blockDim.x) {
        int s = cU[0][t] + cU[1][t] + cU[2][t] + cU[3][t];
        if (s > 0) atomicAdd(&bcntU[t], s);
    }
    for (int t = threadIdx.x; t < NBUCKI; t += blockDim.x) {
        int s = cI[0][t] + cI[1][t] + cI[2][t] + cI[3][t];
        if (s > 0) atomicAdd(&bcntI[t], s);
    }
}

__global__ void bucket_scan(const int* __restrict__ bcntU, const int* __restrict__ bcntI,
                            int* __restrict__ bofsU, int* __restrict__ bofsI,
                            int* __restrict__ bcurU, int* __restrict__ bcurI) {
    __shared__ int ls[256];
    const int t = threadIdx.x;
    int v = (t < NBUCKU) ? bcntU[t] : 0;
    ls[t] = v;
    __syncthreads();
    for (int off = 1; off < 256; off <<= 1) {
        int u = (t >= off) ? ls[t - off] : 0;
        __syncthreads();
        ls[t] += u;
        __syncthreads();
    }
    if (t < NBUCKU) {
        int excl = ls[t] - v;
        bofsU[t] = excl;
        bcurU[t] = excl;
    }
    if (t == NBUCKU - 1) bofsU[NBUCKU] = ls[t];
    __syncthreads();
    v = (t < NBUCKI) ? bcntI[t] : 0;
    ls[t] = v;
    __syncthreads();
    for (int off = 1; off < 256; off <<= 1) {
        int u = (t >= off) ? ls[t - off] : 0;
        __syncthreads();
        ls[t] += u;
        __syncthreads();
    }
    if (t < NBUCKI) {
        int excl = ls[t] - v;
        bofsI[t] = excl;
        bcurI[t] = excl;
    }
    __syncthreads();
    if (t == NBUCKI - 1) bofsI[NBUCKI] = ls[t];
}

__global__ void scatter1(const int* __restrict__ row, const int* __restrict__ col,
                         int* __restrict__ bcurU, int* __restrict__ bcurI,
                         int* __restrict__ stU, int* __restrict__ stI, int nnz) {
    __shared__ int cU[NREP][NBUCKU];
    __shared__ int cI[NREP][NBUCKI];
    const int chunk = (nnz + S1_BLOCKS - 1) / S1_BLOCKS;
    const int b0 = blockIdx.x * chunk;
    const int e0 = min(b0 + chunk, nnz);
    const int sw = threadIdx.x >> 6;
    for (int t = threadIdx.x; t < NREP * NBUCKU; t += blockDim.x) (&cU[0][0])[t] = 0;
    for (int t = threadIdx.x; t < NREP * NBUCKI; t += blockDim.x) (&cI[0][0])[t] = 0;
    __syncthreads();
    for (int i = b0 + threadIdx.x; i < e0; i += blockDim.x) {
        atomicAdd(&cU[sw][row[i] >> BSHIFT], 1);
        atomicAdd(&cI[sw][col[i] >> BSHIFT], 1);
    }
    __syncthreads();
    for (int t = threadIdx.x; t < NBUCKU; t += blockDim.x) {
        int c0 = cU[0][t], c1 = cU[1][t], c2 = cU[2][t], c3 = cU[3][t];
        int tot = c0 + c1 + c2 + c3;
        int base = (tot > 0) ? atomicAdd(&bcurU[t], tot) : 0;
        cU[0][t] = base;
        cU[1][t] = base + c0;
        cU[2][t] = base + c0 + c1;
        cU[3][t] = base + c0 + c1 + c2;
    }
    for (int t = threadIdx.x; t < NBUCKI; t += blockDim.x) {
        int c0 = cI[0][t], c1 = cI[1][t], c2 = cI[2][t], c3 = cI[3][t];
        int tot = c0 + c1 + c2 + c3;
        int base = (tot > 0) ? atomicAdd(&bcurI[t], tot) : 0;
        cI[0][t] = base;
        cI[1][t] = base + c0;
        cI[2][t] = base + c0 + c1;
        cI[3][t] = base + c0 + c1 + c2;
    }
    __syncthreads();
    for (int i = b0 + threadIdx.x; i < e0; i += blockDim.x) {
        int r = row[i], c = col[i];
        int pu = atomicAdd(&cU[sw][r >> BSHIFT], 1);
        stU[pu] = ((r & (BROWS - 1)) << 17) | c;
        int pi = atomicAdd(&cI[sw][c >> BSHIFT], 1);
        stI[pi] = ((c & (BROWS - 1)) << 17) | r;
    }
}

__global__ void scatter2(const int* __restrict__ bofs, const int* __restrict__ st,
                         int* __restrict__ ptr, int* __restrict__ outIdx, int nrows) {
    __shared__ int deg[BROWS];
    __shared__ int ps[256];
    __shared__ int cur[BROWS];
    const int rbase = blockIdx.x << BSHIFT;
    const int nr = min(BROWS, nrows - rbase);
    const int lo = bofs[blockIdx.x];
    const int hi = bofs[blockIdx.x + 1];
    const int t = threadIdx.x;
    deg[2 * t] = 0;
    deg[2 * t + 1] = 0;
    __syncthreads();
    for (int j = lo + t; j < hi; j += 256)
        atomicAdd(&deg[st[j] >> 17], 1);
    __syncthreads();
    int a = deg[2 * t];
    int b = deg[2 * t + 1];
    ps[t] = a + b;
    __syncthreads();
    for (int off = 1; off < 256; off <<= 1) {
        int u = (t >= off) ? ps[t - off] : 0;
        __syncthreads();
        ps[t] += u;
        __syncthreads();
    }
    int excl = (t > 0) ? ps[t - 1] : 0;
    int p0 = lo + excl;
    int p1 = p0 + a;
    cur[2 * t] = p0;
    cur[2 * t + 1] = p1;
    if (2 * t < nr)     ptr[rbase + 2 * t] = p0;
    if (2 * t + 1 < nr) ptr[rbase + 2 * t + 1] = p1;
    if (t == 0 && rbase + BROWS >= nrows) ptr[nrows] = hi;
    __syncthreads();
    for (int j = lo + t; j < hi; j += 256) {
        int v = st[j];
        int p = atomicAdd(&cur[v >> 17], 1);
        outIdx[p] = v & 0x1FFFF;
    }
}

__global__ void scale_k(const int* __restrict__ uptr, const int* __restrict__ iptr,
                        float* __restrict__ du2, float* __restrict__ di2,
                        float* __restrict__ dis) {
    int t = blockIdx.x * blockDim.x + threadIdx.x;
    if (t < NUSERS) {
        int d = uptr[t + 1] - uptr[t];
        du2[t] = (d > 0) ? 1.0f / (float)d : 0.0f;
    }
    if (t < NITEMS) {
        int d = iptr[t + 1] - iptr[t];
        di2[t] = (d > 0) ? 1.0f / (float)d : 0.0f;
        dis[t] = (d > 0) ? 1.0f / sqrtf((float)d) : 0.0f;
    }
}

// ---------------------------------------------------------------------------
// 2-row fp16 gather core (R11 shape + packed adds) -- for deg~16 user rows
// ---------------------------------------------------------------------------
__device__ __forceinline__ void gather2_h(const int* __restrict__ ptr,
                                          const int* __restrict__ idx,
                                          const Half4* __restrict__ x,
                                          int r0, int r1, int sub, int bh,
                                          float4& a0, float4& a1) {
    const int b0 = ptr[r0], e0 = ptr[r0 + 1];
    const int b1 = ptr[r1], e1 = ptr[r1 + 1];
    const int n0 = (e0 - b0) >> 4, n1 = (e1 - b1) >> 4;
    int j0 = b0 + (sub << 2), j1 = b1 + (sub << 2);
    const int nmax = max(n0, n1);
    for (int it = 0; it < nmax; ++it) {
        if (it < n0) {
            int i0 = idx[j0], i1 = idx[j0 + 1], i2 = idx[j0 + 2], i3 = idx[j0 + 3];
            Half4 v0 = x[(size_t)i0 * 16 + bh];
            Half4 v1 = x[(size_t)i1 * 16 + bh];
            Half4 v2 = x[(size_t)i2 * 16 + bh];
            Half4 v3 = x[(size_t)i3 * 16 + bh];
            acc_pk(a0, v0, v1, v2, v3);
            j0 += 16;
        }
        if (it < n1) {
            int i0 = idx[j1], i1 = idx[j1 + 1], i2 = idx[j1 + 2], i3 = idx[j1 + 3];
            Half4 v0 = x[(size_t)i0 * 16 + bh];
            Half4 v1 = x[(size_t)i1 * 16 + bh];
            Half4 v2 = x[(size_t)i2 * 16 + bh];
            Half4 v3 = x[(size_t)i3 * 16 + bh];
            acc_pk(a1, v0, v1, v2, v3);
            j1 += 16;
        }
    }
    for (int j = b0 + (n0 << 4) + sub; j < e0; j += 4) acc_h4(a0, x[(size_t)idx[j] * 16 + bh]);
    for (int j = b1 + (n1 << 4) + sub; j < e1; j += 4) acc_h4(a1, x[(size_t)idx[j] * 16 + bh]);
    a0.x += __shfl_xor(a0.x, 16); a0.y += __shfl_xor(a0.y, 16);
    a0.z += __shfl_xor(a0.z, 16); a0.w += __shfl_xor(a0.w, 16);
    a0.x += __shfl_xor(a0.x, 32); a0.y += __shfl_xor(a0.y, 32);
    a0.z += __shfl_xor(a0.z, 32); a0.w += __shfl_xor(a0.w, 32);
    a1.x += __shfl_xor(a1.x, 16); a1.y += __shfl_xor(a1.y, 16);
    a1.z += __shfl_xor(a1.z, 16); a1.w += __shfl_xor(a1.w, 16);
    a1.x += __shfl_xor(a1.x, 32); a1.y += __shfl_xor(a1.y, 32);
    a1.z += __shfl_xor(a1.z, 32); a1.w += __shfl_xor(a1.w, 32);
}

// user side (2-row): y[u] = du2[u] * sum tauH[col]
__global__ void spmm_user(const int* __restrict__ ptr, const int* __restrict__ idx,
                          const float* __restrict__ du2,
                          const Half4* __restrict__ tauH, Half4* __restrict__ y) {
    const int lane = threadIdx.x & 63;
    const int w = (blockIdx.x * blockDim.x + threadIdx.x) >> 6;
    const int H = NUSERS / 2;
    if (w >= H) return;
    const int r0 = w, r1 = w + H;
    const int sub = lane >> 4;
    const int bh  = lane & 15;
    float4 a0 = {0.f, 0.f, 0.f, 0.f}, a1 = {0.f, 0.f, 0.f, 0.f};
    gather2_h(ptr, idx, tauH, r0, r1, sub, bh, a0, a1);
    if (sub == 0) {
        float s0 = du2[r0];
        y[(size_t)r0 * 16 + bh] = to_h4(s0 * a0.x, s0 * a0.y, s0 * a0.z, s0 * a0.w);
        float s1 = du2[r1];
        y[(size_t)r1 * 16 + bh] = to_h4(s1 * a1.x, s1 * a1.y, s1 * a1.z, s1 * a1.w);
    }
}

// ---------------------------------------------------------------------------
// 4-row fp16 gather core (R12) -- for deg~32 item rows
// ---------------------------------------------------------------------------
__device__ __forceinline__ void gather4_h(const int* __restrict__ ptr,
                                          const int* __restrict__ idx,
                                          const Half4* __restrict__ x,
                                          const int* r, int sub, int bh,
                                          float4* a) {
    int b[4], e[4], n[4], j[4];
    int nmax = 0;
    #pragma unroll
    for (int q = 0; q < 4; ++q) {
        b[q] = ptr[r[q]];
        e[q] = ptr[r[q] + 1];
        n[q] = (e[q] - b[q]) >> 4;
        j[q] = b[q] + (sub << 2);
        nmax = max(nmax, n[q]);
    }
    for (int it = 0; it < nmax; ++it) {
        #pragma unroll
        for (int q = 0; q < 4; ++q) {
            if (it < n[q]) {
                int i0 = idx[j[q]], i1 = idx[j[q] + 1];
                int i2 = idx[j[q] + 2], i3 = idx[j[q] + 3];
                Half4 v0 = x[(size_t)i0 * 16 + bh];
                Half4 v1 = x[(size_t)i1 * 16 + bh];
                Half4 v2 = x[(size_t)i2 * 16 + bh];
                Half4 v3 = x[(size_t)i3 * 16 + bh];
                acc_pk(a[q], v0, v1, v2, v3);
                j[q] += 16;
            }
        }
    }
    #pragma unroll
    for (int q = 0; q < 4; ++q)
        for (int jj = b[q] + (n[q] << 4) + sub; jj < e[q]; jj += 4)
            acc_h4(a[q], x[(size_t)idx[jj] * 16 + bh]);
    #pragma unroll
    for (int q = 0; q < 4; ++q) {
        a[q].x += __shfl_xor(a[q].x, 16); a[q].y += __shfl_xor(a[q].y, 16);
        a[q].z += __shfl_xor(a[q].z, 16); a[q].w += __shfl_xor(a[q].w, 16);
        a[q].x += __shfl_xor(a[q].x, 32); a[q].y += __shfl_xor(a[q].y, 32);
        a[q].z += __shfl_xor(a[q].z, 32); a[q].w += __shfl_xor(a[q].w, 32);
    }
}

// item, first step: tau1 = tau0 - 2*di2*z ; write fp32 + fp16 (no obuf)
__global__ void spmm_item_first(const int* __restrict__ ptr, const int* __restrict__ idx,
                                const float* __restrict__ di2, const Half4* __restrict__ y,
                                const float* __restrict__ tau0, float* __restrict__ tau1,
                                Half4* __restrict__ tauH1) {
    const int lane = threadIdx.x & 63;
    const int w = (blockIdx.x * blockDim.x + threadIdx.x) >> 6;
    const int H = NITEMS / 4;
    if (w >= H) return;
    int r[4] = {w, w + H, w + 2 * H, w + 3 * H};
    const int sub = lane >> 4;
    const int bh  = lane & 15;
    float4 a[4] = {{0,0,0,0},{0,0,0,0},{0,0,0,0},{0,0,0,0}};
    gather4_h(ptr, idx, y, r, sub, bh, a);
    if (sub == 0) {
        #pragma unroll
        for (int q = 0; q < 4; ++q) {
            float s2 = 2.0f * di2[r[q]];
            size_t base = (size_t)r[q] * BATCH + (bh << 2);
            float4 t0v = *(const float4*)&tau0[base];
            float4 t;
            t.x = t0v.x - s2 * a[q].x; t.y = t0v.y - s2 * a[q].y;
            t.z = t0v.z - s2 * a[q].z; t.w = t0v.w - s2 * a[q].w;
            *(float4*)&tau1[base] = t;
            tauH1[(size_t)r[q] * 16 + bh] = to_h4(t.x, t.y, t.z, t.w);
        }
    }
}

// item, general step: t2 = 2*t1 - 4*di2*z - t0 ; write fp32 + fp16 (no obuf)
__global__ void spmm_item_k(const int* __restrict__ ptr, const int* __restrict__ idx,
                            const float* __restrict__ di2, const Half4* __restrict__ y,
                            const float* __restrict__ tau1, float* __restrict__ tau0,
                            Half4* __restrict__ tauHk) {
    const int lane = threadIdx.x & 63;
    const int w = (blockIdx.x * blockDim.x + threadIdx.x) >> 6;
    const int H = NITEMS / 4;
    if (w >= H) return;
    int r[4] = {w, w + H, w + 2 * H, w + 3 * H};
    const int sub = lane >> 4;
    const int bh  = lane & 15;
    float4 a[4] = {{0,0,0,0},{0,0,0,0},{0,0,0,0},{0,0,0,0}};
    gather4_h(ptr, idx, y, r, sub, bh, a);
    if (sub == 0) {
        #pragma unroll
        for (int q = 0; q < 4; ++q) {
            float s4 = 4.0f * di2[r[q]];
            size_t base = (size_t)r[q] * BATCH + (bh << 2);
            float4 t1v = *(const float4*)&tau1[base];
            float4 t0v = *(const float4*)&tau0[base];
            float4 t2;
            t2.x = 2.0f * t1v.x - s4 * a[q].x - t0v.x;
            t2.y = 2.0f * t1v.y - s4 * a[q].y - t0v.y;
            t2.z = 2.0f * t1v.z - s4 * a[q].z - t0v.z;
            t2.w = 2.0f * t1v.w - s4 * a[q].w - t0v.w;
            *(float4*)&tau0[base] = t2;
            tauHk[(size_t)r[q] * 16 + bh] = to_h4(t2.x, t2.y, t2.z, t2.w);
        }
    }
}

// ---------------------------------------------------------------------------
// Host-side exact replica of reference cheby_coeffs
// ---------------------------------------------------------------------------
static void cheby_coeffs_host(float* c) {
    const int order = ORDER, flatness = 2;
    const double PI = 3.14159265358979323846;
    double tgt[ORDER + 1], nodes[ORDER + 1];
    for (int x = 0; x <= order; ++x) {
        double xv = cos((double)(order - x) / order * PI);
        xv = nearbyint(xv * 1000.0) / 1000.0;
        double t = (xv < 0.0) ? pow(-xv, (double)flatness) * 0.5 + 0.5
                              : pow(xv, (double)flatness) * (-0.5) + 0.5;
        tgt[x] = nearbyint(t * 1000.0) / 1000.0;
    }
    for (int k = 1; k <= order + 1; ++k)
        nodes[k - 1] = cos((order + 1 + 0.5 - k) / (double)(order + 1) * PI);

    double prev[ORDER + 1], cur[ORDER + 1], nxt[ORDER + 1];
    double sums[ORDER + 1];
    double s0 = 0, s1 = 0;
    for (int i = 0; i <= order; ++i) {
        prev[i] = tgt[i];
        cur[i]  = nodes[i] * tgt[i];
        s0 += prev[i];
        s1 += cur[i];
    }
    sums[0] = s0; sums[1] = s1;
    for (int j = 2; j <= order; ++j) {
        double s = 0;
        for (int i = 0; i <= order; ++i) {
            nxt[i] = nodes[i] * cur[i] * 2.0 - prev[i];
            s += nxt[i];
        }
        sums[j] = s;
        for (int i = 0; i <= order; ++i) { prev[i] = cur[i]; cur[i] = nxt[i]; }
    }
    for (int j = 0; j <= order; ++j)
        c[j] = (float)(sums[j] * (2.0 / (order + 1)));
    c[0] *= 0.5f;
}

extern "C" void kernel_launch(void* const* d_in, const int* in_sizes, int n_in,
                              void* d_out, int out_size, void* d_ws, size_t ws_size,
                              hipStream_t stream) {
    const float* signal = (const float*)d_in[0];   // [BATCH, NITEMS]
    const int*   row    = (const int*)d_in[2];     // [NNZ] -> users
    const int*   col    = (const int*)d_in[3];     // [NNZ] -> items
    const int nnz = in_sizes[1];

    char* wsb = (char*)d_ws;
    size_t off = 0;
    auto carve = [&](size_t nbytes) {
        void* p = wsb + off;
        off += (nbytes + 255) & ~(size_t)255;
        return p;
    };
    const size_t NB = (size_t)NITEMS * BATCH;
    const size_t UB = (size_t)NUSERS * BATCH;
    float*  tauA   = (float*)carve(NB * 4);
    float*  tauB   = (float*)carve(NB * 4);
    __half* tauHall = (__half*)carve((ORDER + 1) * NB * 2);  // 9 x 6.4MB fp16 tau_k
    Half4*  ybuf   = (Half4*)carve(UB * 2);
    int*    uptr   = (int*)carve((NUSERS + 1) * 4);
    int*    iptr   = (int*)carve((NITEMS + 1) * 4);
    int*    bcntU  = (int*)carve(NBUCKU * 4);
    int*    bcntI  = (int*)carve(NBUCKI * 4);
    int*    bofsU  = (int*)carve((NBUCKU + 1) * 4);
    int*    bofsI  = (int*)carve((NBUCKI + 1) * 4);
    int*    bcurU  = (int*)carve(NBUCKU * 4);
    int*    bcurI  = (int*)carve(NBUCKI * 4);
    float*  du2    = (float*)carve(NUSERS * 4);
    float*  di2    = (float*)carve(NITEMS * 4);
    float*  dis    = (float*)carve(NITEMS * 4);
    int*    ucol   = (int*)carve((size_t)nnz * 4);
    int*    irow   = (int*)carve((size_t)nnz * 4);
    // staging aliases tauHall (dead until transpose_scale, which runs after build)
    int*    stU    = (int*)tauHall;
    int*    stI    = (int*)tauHall + nnz;
    (void)ws_size;

    float c[ORDER + 1];
    cheby_coeffs_host(c);
    Coeffs cf;
    float csum = 0.f;
    for (int k = 0; k <= ORDER; ++k) { cf.v[k] = c[k]; csum += c[k]; }

    // ---- bucket-level histogram + scan ----
    hipMemsetAsync(bcntU, 0, (NBUCKU + NBUCKI + 64) * 4, stream);
    bucket_hist<<<S1_BLOCKS, 256, 0, stream>>>(row, col, bcntU, bcntI, nnz);
    bucket_scan<<<1, 256, 0, stream>>>(bcntU, bcntI, bofsU, bofsI, bcurU, bcurI);

    // ---- binned scatter + per-bucket CSR finalize ----
    scatter1<<<S1_BLOCKS, 256, 0, stream>>>(row, col, bcurU, bcurI, stU, stI, nnz);
    scatter2<<<NBUCKU, 256, 0, stream>>>(bofsU, stU, uptr, ucol, NUSERS);
    scatter2<<<NBUCKI, 256, 0, stream>>>(bofsI, stI, iptr, irow, NITEMS);

    // ---- scales ----
    scale_k<<<(NUSERS + 255) / 256, 256, 0, stream>>>(uptr, iptr, du2, di2, dis);

    // ---- tau0 (fp32 + fp16 slot 0) ----
    dim3 tb(32, 8);
    transpose_scale_k<<<dim3((NITEMS + 31) / 32, (BATCH + 31) / 32), tb, 0, stream>>>(
        signal, dis, tauA, tauHall);

    const int ug = ((NUSERS / 2) * 64 + 255) / 256;   // user: 2 rows/wave
    const int ig = ((NITEMS / 4) * 64 + 255) / 256;   // item: 4 rows/wave

    // ---- k = 1 ----
    spmm_user<<<ug, 256, 0, stream>>>(uptr, ucol, du2, (const Half4*)tauHall, ybuf);
    spmm_item_first<<<ig, 256, 0, stream>>>(iptr, irow, di2, ybuf, tauA, tauB,
                                            (Half4*)(tauHall + NB));

    float* t0 = tauA;
    float* t1 = tauB;
    for (int k = 2; k <= ORDER; ++k) {
        spmm_user<<<ug, 256, 0, stream>>>(uptr, ucol, du2,
                                          (const Half4*)(tauHall + (size_t)(k - 1) * NB), ybuf);
        spmm_item_k<<<ig, 256, 0, stream>>>(iptr, irow, di2, ybuf, t1, t0,
                                            (Half4*)(tauHall + (size_t)k * NB));
        float* tmp = t0; t0 = t1; t1 = tmp;
    }

    // ---- d_out = sqrt(di) * sum_k c_k tauH_k, transposed ----
    transpose_out_k<<<dim3((BATCH + 31) / 32, (NITEMS + 31) / 32), tb, 0, stream>>>(
        tauHall, signal, iptr, csum, cf, (float*)d_out);
}

// Round 14
// 770.986 us; speedup vs baseline: 1.1655x; 1.1308x over previous
//
#include <hip/hip_runtime.h>
#include <hip/hip_fp16.h>
#include <math.h>

#define NUSERS 100000
#define NITEMS 50000
#define BATCH  64
#define ORDER  8
#define BSHIFT 9                                   // 512 rows per bucket
#define BROWS  (1 << BSHIFT)
#define NBUCKU ((NUSERS + BROWS - 1) >> BSHIFT)    // 196
#define NBUCKI ((NITEMS + BROWS - 1) >> BSHIFT)    // 98
#define CAPU 16384                                 // padded-edge capacity / bucket
#define CAPI 24576
#define S1_BLOCKS 512
#define NREP 4

// ---------------------------------------------------------------------------
// R14: every CSR row padded to a multiple of 16 edges with a dummy index to a
// dedicated zero row -> gather kernels have NO tail loops (Poisson tails were
// ~45%/23% of user/item edges at 1/4 MLP). Fixed-capacity buckets remove
// bucket_hist/bucket_scan/memset; scales (1/deg, rsqrt) inlined, scale_k gone.
// deg[] arrays carry actual degrees (ptr[r+1] is no longer the row end).
// ---------------------------------------------------------------------------

struct __align__(8) Half4 { __half2 a, b; };
struct Coeffs { float v[ORDER + 1]; };

#define SLOT ((size_t)(NITEMS + 1) * BATCH)        // fp16 tau slot incl. zero row

__device__ __forceinline__ void acc_pk(float4& acc, Half4 v0, Half4 v1,
                                       Half4 v2, Half4 v3) {
    __half2 sa = __hadd2(__hadd2(v0.a, v1.a), __hadd2(v2.a, v3.a));
    __half2 sb = __hadd2(__hadd2(v0.b, v1.b), __hadd2(v2.b, v3.b));
    float2 fa = __half22float2(sa);
    float2 fb = __half22float2(sb);
    acc.x += fa.x; acc.y += fa.y; acc.z += fb.x; acc.w += fb.y;
}

__device__ __forceinline__ Half4 to_h4(float x, float y, float z, float w) {
    Half4 h;
    h.a = __floats2half2_rn(x, y);
    h.b = __floats2half2_rn(z, w);
    return h;
}

// ---------------------------------------------------------------------------
// CSR build
// ---------------------------------------------------------------------------
__global__ void init_bcur(int* __restrict__ bcurU, int* __restrict__ bcurI) {
    int t = blockIdx.x * blockDim.x + threadIdx.x;
    if (t < NBUCKU) bcurU[t] = t * CAPU;
    if (t < NBUCKI) bcurI[t] = t * CAPI;
}

// zero the dummy rows (run AFTER scatter2: staging aliases tauHall)
__global__ void zero_pads(__half* __restrict__ tauHall, __half* __restrict__ ybuf) {
    int t = threadIdx.x;
    for (int k = 0; k <= ORDER; ++k)
        if (t < BATCH) tauHall[(size_t)k * SLOT + (size_t)NITEMS * BATCH + t] = __float2half(0.f);
    if (t < BATCH) ybuf[(size_t)NUSERS * BATCH + t] = __float2half(0.f);
}

// block-aggregated bucket scatter into fixed-capacity staging (R11 core)
__global__ void scatter1(const int* __restrict__ row, const int* __restrict__ col,
                         int* __restrict__ bcurU, int* __restrict__ bcurI,
                         int* __restrict__ stU, int* __restrict__ stI, int nnz) {
    __shared__ int cU[NREP][NBUCKU];
    __shared__ int cI[NREP][NBUCKI];
    const int chunk = (nnz + S1_BLOCKS - 1) / S1_BLOCKS;
    const int b0 = blockIdx.x * chunk;
    const int e0 = min(b0 + chunk, nnz);
    const int sw = threadIdx.x >> 6;
    for (int t = threadIdx.x; t < NREP * NBUCKU; t += blockDim.x) (&cU[0][0])[t] = 0;
    for (int t = threadIdx.x; t < NREP * NBUCKI; t += blockDim.x) (&cI[0][0])[t] = 0;
    __syncthreads();
    for (int i = b0 + threadIdx.x; i < e0; i += blockDim.x) {
        atomicAdd(&cU[sw][row[i] >> BSHIFT], 1);
        atomicAdd(&cI[sw][col[i] >> BSHIFT], 1);
    }
    __syncthreads();
    for (int t = threadIdx.x; t < NBUCKU; t += blockDim.x) {
        int c0 = cU[0][t], c1 = cU[1][t], c2 = cU[2][t], c3 = cU[3][t];
        int tot = c0 + c1 + c2 + c3;
        int base = (tot > 0) ? atomicAdd(&bcurU[t], tot) : 0;
        cU[0][t] = base;
        cU[1][t] = base + c0;
        cU[2][t] = base + c0 + c1;
        cU[3][t] = base + c0 + c1 + c2;
    }
    for (int t = threadIdx.x; t < NBUCKI; t += blockDim.x) {
        int c0 = cI[0][t], c1 = cI[1][t], c2 = cI[2][t], c3 = cI[3][t];
        int tot = c0 + c1 + c2 + c3;
        int base = (tot > 0) ? atomicAdd(&bcurI[t], tot) : 0;
        cI[0][t] = base;
        cI[1][t] = base + c0;
        cI[2][t] = base + c0 + c1;
        cI[3][t] = base + c0 + c1 + c2;
    }
    __syncthreads();
    for (int i = b0 + threadIdx.x; i < e0; i += blockDim.x) {
        int r = row[i], c = col[i];
        int pu = atomicAdd(&cU[sw][r >> BSHIFT], 1);
        stU[pu] = ((r & (BROWS - 1)) << 17) | c;
        int pi = atomicAdd(&cI[sw][c >> BSHIFT], 1);
        stI[pi] = ((c & (BROWS - 1)) << 17) | r;
    }
}

// per-bucket finalize: LDS degrees -> padded prefix scan -> global ptr/deg ->
// scatter edges -> fill pad slots with dummy index
__global__ void scatter2(const int* __restrict__ bcur, const int* __restrict__ st,
                         int* __restrict__ ptr, int* __restrict__ degOut,
                         int* __restrict__ outIdx, int nrows, int cap, int dummyIdx) {
    __shared__ int deg[BROWS];
    __shared__ int ps[256];
    __shared__ int cur[BROWS];
    __shared__ int rs[BROWS];
    const int rbase = blockIdx.x << BSHIFT;
    const int nr = min(BROWS, nrows - rbase);
    const int lo = blockIdx.x * cap;
    const int hi = bcur[blockIdx.x];       // absolute end of staged records
    const int t = threadIdx.x;
    deg[2 * t] = 0;
    deg[2 * t + 1] = 0;
    __syncthreads();
    for (int j = lo + t; j < hi; j += 256)
        atomicAdd(&deg[st[j] >> 17], 1);
    __syncthreads();
    int a = deg[2 * t];
    int b = deg[2 * t + 1];
    int pa = (a + 15) & ~15;
    int pb = (b + 15) & ~15;
    ps[t] = pa + pb;
    __syncthreads();
    for (int off = 1; off < 256; off <<= 1) {
        int u = (t >= off) ? ps[t - off] : 0;
        __syncthreads();
        ps[t] += u;
        __syncthreads();
    }
    int excl = (t > 0) ? ps[t - 1] : 0;
    int p0 = lo + excl;
    int p1 = p0 + pa;
    rs[2 * t] = p0;
    rs[2 * t + 1] = p1;
    cur[2 * t] = p0;
    cur[2 * t + 1] = p1;
    if (2 * t < nr)     { ptr[rbase + 2 * t] = p0;     degOut[rbase + 2 * t] = a; }
    if (2 * t + 1 < nr) { ptr[rbase + 2 * t + 1] = p1; degOut[rbase + 2 * t + 1] = b; }
    __syncthreads();
    for (int j = lo + t; j < hi; j += 256) {
        int v = st[j];
        int p = atomicAdd(&cur[v >> 17], 1);
        outIdx[p] = v & 0x1FFFF;
    }
    __syncthreads();
    // pad fill: [start+deg, start+pdeg) <- dummyIdx
    for (int i = t; i < nr; i += 256) {
        int endReal = cur[i];                       // == rs[i] + deg[i]
        int endPad  = rs[i] + ((deg[i] + 15) & ~15);
        for (int j = endReal; j < endPad; ++j) outIdx[j] = dummyIdx;
    }
}

// ---------------------------------------------------------------------------
// transposes (scales inlined from deg arrays)
// ---------------------------------------------------------------------------
__global__ void transpose_scale_k(const float* __restrict__ in,   // [BATCH][NITEMS]
                                  const int* __restrict__ ideg,
                                  float* __restrict__ out,        // fp32 tau0
                                  __half* __restrict__ outH) {    // fp16 slot 0
    __shared__ float tile[32][33];
    const int cb = blockIdx.x * 32;   // item base
    const int rb = blockIdx.y * 32;   // batch base
    for (int i = threadIdx.y; i < 32; i += 8) {
        int r = rb + i, c = cb + threadIdx.x;
        if (r < BATCH && c < NITEMS) tile[i][threadIdx.x] = in[(size_t)r * NITEMS + c];
    }
    __syncthreads();
    for (int i = threadIdx.y; i < 32; i += 8) {
        int c = cb + i, r = rb + threadIdx.x;   // c = item, r = batch
        if (c < NITEMS && r < BATCH) {
            int d = ideg[c];
            float dis = (d > 0) ? rsqrtf((float)d) : 0.0f;
            float v = dis * tile[threadIdx.x][i];
            out[(size_t)c * BATCH + r] = v;
            outH[(size_t)c * BATCH + r] = __float2half(v);
        }
    }
}

__global__ void transpose_out_k(const __half* __restrict__ tauHall,
                                const float* __restrict__ signal,
                                const int* __restrict__ ideg, float csum, Coeffs cf,
                                float* __restrict__ out) {
    __shared__ float tile[32][33];
    const int cb = blockIdx.x * 32;   // batch base
    const int rb = blockIdx.y * 32;   // item base
    for (int i = threadIdx.y; i < 32; i += 8) {
        int r = rb + i, c = cb + threadIdx.x;
        if (r < NITEMS && c < BATCH) {
            size_t base = (size_t)r * BATCH + c;
            float s = 0.f;
            #pragma unroll
            for (int k = 0; k <= ORDER; ++k)
                s += cf.v[k] * __half2float(tauHall[(size_t)k * SLOT + base]);
            tile[i][threadIdx.x] = s;
        }
    }
    __syncthreads();
    for (int i = threadIdx.y; i < 32; i += 8) {
        int c = cb + i, r = rb + threadIdx.x;   // c = batch, r = item
        if (c < BATCH && r < NITEMS) {
            int d = ideg[r];
            float v = (d > 0) ? sqrtf((float)d) * tile[threadIdx.x][i]
                              : csum * signal[(size_t)c * NITEMS + r];
            out[(size_t)c * NITEMS + r] = v;
        }
    }
}

// ---------------------------------------------------------------------------
// SpMMs -- padded rows: exactly n=(deg+15)>>4 macro-iters, no tails.
// ---------------------------------------------------------------------------

// user side (2 rows/wave): y[u] = (1/deg_u) * sum tauH[col]
__global__ void spmm_user(const int* __restrict__ ptr, const int* __restrict__ deg,
                          const int* __restrict__ idx,
                          const Half4* __restrict__ tauH, Half4* __restrict__ y) {
    const int lane = threadIdx.x & 63;
    const int w = (blockIdx.x * blockDim.x + threadIdx.x) >> 6;
    const int H = NUSERS / 2;
    if (w >= H) return;
    const int r0 = w, r1 = w + H;
    const int sub = lane >> 4;
    const int bh  = lane & 15;
    const int b0 = ptr[r0], d0 = deg[r0], n0 = (d0 + 15) >> 4;
    const int b1 = ptr[r1], d1 = deg[r1], n1 = (d1 + 15) >> 4;
    int j0 = b0 + (sub << 2), j1 = b1 + (sub << 2);
    float4 a0 = {0.f, 0.f, 0.f, 0.f}, a1 = {0.f, 0.f, 0.f, 0.f};
    const int nmax = max(n0, n1);
    for (int it = 0; it < nmax; ++it) {
        if (it < n0) {
            int i0 = idx[j0], i1 = idx[j0 + 1], i2 = idx[j0 + 2], i3 = idx[j0 + 3];
            Half4 v0 = tauH[(size_t)i0 * 16 + bh];
            Half4 v1 = tauH[(size_t)i1 * 16 + bh];
            Half4 v2 = tauH[(size_t)i2 * 16 + bh];
            Half4 v3 = tauH[(size_t)i3 * 16 + bh];
            acc_pk(a0, v0, v1, v2, v3);
            j0 += 16;
        }
        if (it < n1) {
            int i0 = idx[j1], i1 = idx[j1 + 1], i2 = idx[j1 + 2], i3 = idx[j1 + 3];
            Half4 v0 = tauH[(size_t)i0 * 16 + bh];
            Half4 v1 = tauH[(size_t)i1 * 16 + bh];
            Half4 v2 = tauH[(size_t)i2 * 16 + bh];
            Half4 v3 = tauH[(size_t)i3 * 16 + bh];
            acc_pk(a1, v0, v1, v2, v3);
            j1 += 16;
        }
    }
    a0.x += __shfl_xor(a0.x, 16); a0.y += __shfl_xor(a0.y, 16);
    a0.z += __shfl_xor(a0.z, 16); a0.w += __shfl_xor(a0.w, 16);
    a0.x += __shfl_xor(a0.x, 32); a0.y += __shfl_xor(a0.y, 32);
    a0.z += __shfl_xor(a0.z, 32); a0.w += __shfl_xor(a0.w, 32);
    a1.x += __shfl_xor(a1.x, 16); a1.y += __shfl_xor(a1.y, 16);
    a1.z += __shfl_xor(a1.z, 16); a1.w += __shfl_xor(a1.w, 16);
    a1.x += __shfl_xor(a1.x, 32); a1.y += __shfl_xor(a1.y, 32);
    a1.z += __shfl_xor(a1.z, 32); a1.w += __shfl_xor(a1.w, 32);
    if (sub == 0) {
        float s0 = (d0 > 0) ? 1.0f / (float)d0 : 0.0f;
        y[(size_t)r0 * 16 + bh] = to_h4(s0 * a0.x, s0 * a0.y, s0 * a0.z, s0 * a0.w);
        float s1 = (d1 > 0) ? 1.0f / (float)d1 : 0.0f;
        y[(size_t)r1 * 16 + bh] = to_h4(s1 * a1.x, s1 * a1.y, s1 * a1.z, s1 * a1.w);
    }
}

// item-side gather core: 4 rows/wave, padded, no tails
__device__ __forceinline__ void gather4_p(const int* __restrict__ idx,
                                          const Half4* __restrict__ y,
                                          const int* b, const int* n,
                                          int sub, int bh, float4* a) {
    int j[4];
    int nmax = 0;
    #pragma unroll
    for (int q = 0; q < 4; ++q) {
        j[q] = b[q] + (sub << 2);
        nmax = max(nmax, n[q]);
    }
    for (int it = 0; it < nmax; ++it) {
        #pragma unroll
        for (int q = 0; q < 4; ++q) {
            if (it < n[q]) {
                int i0 = idx[j[q]], i1 = idx[j[q] + 1];
                int i2 = idx[j[q] + 2], i3 = idx[j[q] + 3];
                Half4 v0 = y[(size_t)i0 * 16 + bh];
                Half4 v1 = y[(size_t)i1 * 16 + bh];
                Half4 v2 = y[(size_t)i2 * 16 + bh];
                Half4 v3 = y[(size_t)i3 * 16 + bh];
                acc_pk(a[q], v0, v1, v2, v3);
                j[q] += 16;
            }
        }
    }
    #pragma unroll
    for (int q = 0; q < 4; ++q) {
        a[q].x += __shfl_xor(a[q].x, 16); a[q].y += __shfl_xor(a[q].y, 16);
        a[q].z += __shfl_xor(a[q].z, 16); a[q].w += __shfl_xor(a[q].w, 16);
        a[q].x += __shfl_xor(a[q].x, 32); a[q].y += __shfl_xor(a[q].y, 32);
        a[q].z += __shfl_xor(a[q].z, 32); a[q].w += __shfl_xor(a[q].w, 32);
    }
}

// item, first step: tau1 = tau0 - (2/deg)*z ; write fp32 + fp16
__global__ void spmm_item_first(const int* __restrict__ ptr, const int* __restrict__ deg,
                                const int* __restrict__ idx, const Half4* __restrict__ y,
                                const float* __restrict__ tau0, float* __restrict__ tau1,
                                Half4* __restrict__ tauH1) {
    const int lane = threadIdx.x & 63;
    const int w = (blockIdx.x * blockDim.x + threadIdx.x) >> 6;
    const int H = NITEMS / 4;
    if (w >= H) return;
    int r[4] = {w, w + H, w + 2 * H, w + 3 * H};
    const int sub = lane >> 4;
    const int bh  = lane & 15;
    int b[4], d[4], n[4];
    #pragma unroll
    for (int q = 0; q < 4; ++q) {
        b[q] = ptr[r[q]];
        d[q] = deg[r[q]];
        n[q] = (d[q] + 15) >> 4;
    }
    float4 a[4] = {{0,0,0,0},{0,0,0,0},{0,0,0,0},{0,0,0,0}};
    gather4_p(idx, y, b, n, sub, bh, a);
    if (sub == 0) {
        #pragma unroll
        for (int q = 0; q < 4; ++q) {
            float inv = (d[q] > 0) ? 1.0f / (float)d[q] : 0.0f;
            float s2 = 2.0f * inv;
            size_t base = (size_t)r[q] * BATCH + (bh << 2);
            float4 t0v = *(const float4*)&tau0[base];
            float4 t;
            t.x = t0v.x - s2 * a[q].x; t.y = t0v.y - s2 * a[q].y;
            t.z = t0v.z - s2 * a[q].z; t.w = t0v.w - s2 * a[q].w;
            *(float4*)&tau1[base] = t;
            tauH1[(size_t)r[q] * 16 + bh] = to_h4(t.x, t.y, t.z, t.w);
        }
    }
}

// item, general step: t2 = 2*t1 - (4/deg)*z - t0 ; write fp32 + fp16
__global__ void spmm_item_k(const int* __restrict__ ptr, const int* __restrict__ deg,
                            const int* __restrict__ idx, const Half4* __restrict__ y,
                            const float* __restrict__ tau1, float* __restrict__ tau0,
                            Half4* __restrict__ tauHk) {
    const int lane = threadIdx.x & 63;
    const int w = (blockIdx.x * blockDim.x + threadIdx.x) >> 6;
    const int H = NITEMS / 4;
    if (w >= H) return;
    int r[4] = {w, w + H, w + 2 * H, w + 3 * H};
    const int sub = lane >> 4;
    const int bh  = lane & 15;
    int b[4], d[4], n[4];
    #pragma unroll
    for (int q = 0; q < 4; ++q) {
        b[q] = ptr[r[q]];
        d[q] = deg[r[q]];
        n[q] = (d[q] + 15) >> 4;
    }
    float4 a[4] = {{0,0,0,0},{0,0,0,0},{0,0,0,0},{0,0,0,0}};
    gather4_p(idx, y, b, n, sub, bh, a);
    if (sub == 0) {
        #pragma unroll
        for (int q = 0; q < 4; ++q) {
            float inv = (d[q] > 0) ? 1.0f / (float)d[q] : 0.0f;
            float s4 = 4.0f * inv;
            size_t base = (size_t)r[q] * BATCH + (bh << 2);
            float4 t1v = *(const float4*)&tau1[base];
            float4 t0v = *(const float4*)&tau0[base];
            float4 t2;
            t2.x = 2.0f * t1v.x - s4 * a[q].x - t0v.x;
            t2.y = 2.0f * t1v.y - s4 * a[q].y - t0v.y;
            t2.z = 2.0f * t1v.z - s4 * a[q].z - t0v.z;
            t2.w = 2.0f * t1v.w - s4 * a[q].w - t0v.w;
            *(float4*)&tau0[base] = t2;
            tauHk[(size_t)r[q] * 16 + bh] = to_h4(t2.x, t2.y, t2.z, t2.w);
        }
    }
}

// ---------------------------------------------------------------------------
// Host-side exact replica of reference cheby_coeffs
// ---------------------------------------------------------------------------
static void cheby_coeffs_host(float* c) {
    const int order = ORDER, flatness = 2;
    const double PI = 3.14159265358979323846;
    double tgt[ORDER + 1], nodes[ORDER + 1];
    for (int x = 0; x <= order; ++x) {
        double xv = cos((double)(order - x) / order * PI);
        xv = nearbyint(xv * 1000.0) / 1000.0;
        double t = (xv < 0.0) ? pow(-xv, (double)flatness) * 0.5 + 0.5
                              : pow(xv, (double)flatness) * (-0.5) + 0.5;
        tgt[x] = nearbyint(t * 1000.0) / 1000.0;
    }
    for (int k = 1; k <= order + 1; ++k)
        nodes[k - 1] = cos((order + 1 + 0.5 - k) / (double)(order + 1) * PI);

    double prev[ORDER + 1], cur[ORDER + 1], nxt[ORDER + 1];
    double sums[ORDER + 1];
    double s0 = 0, s1 = 0;
    for (int i = 0; i <= order; ++i) {
        prev[i] = tgt[i];
        cur[i]  = nodes[i] * tgt[i];
        s0 += prev[i];
        s1 += cur[i];
    }
    sums[0] = s0; sums[1] = s1;
    for (int j = 2; j <= order; ++j) {
        double s = 0;
        for (int i = 0; i <= order; ++i) {
            nxt[i] = nodes[i] * cur[i] * 2.0 - prev[i];
            s += nxt[i];
        }
        sums[j] = s;
        for (int i = 0; i <= order; ++i) { prev[i] = cur[i]; cur[i] = nxt[i]; }
    }
    for (int j = 0; j <= order; ++j)
        c[j] = (float)(sums[j] * (2.0 / (order + 1)));
    c[0] *= 0.5f;
}

extern "C" void kernel_launch(void* const* d_in, const int* in_sizes, int n_in,
                              void* d_out, int out_size, void* d_ws, size_t ws_size,
                              hipStream_t stream) {
    const float* signal = (const float*)d_in[0];   // [BATCH, NITEMS]
    const int*   row    = (const int*)d_in[2];     // [NNZ] -> users
    const int*   col    = (const int*)d_in[3];     // [NNZ] -> items
    const int nnz = in_sizes[1];

    char* wsb = (char*)d_ws;
    size_t off = 0;
    auto carve = [&](size_t nbytes) {
        void* p = wsb + off;
        off += (nbytes + 255) & ~(size_t)255;
        return p;
    };
    const size_t NB = (size_t)NITEMS * BATCH;
    const size_t NEU = (size_t)NBUCKU * CAPU;      // padded user-edge capacity
    const size_t NEI = (size_t)NBUCKI * CAPI;      // padded item-edge capacity
    float*  tauA   = (float*)carve(NB * 4);
    float*  tauB   = (float*)carve(NB * 4);
    __half* tauHall = (__half*)carve((ORDER + 1) * SLOT * 2);  // 9 slots + zero rows
    Half4*  ybuf   = (Half4*)carve(((size_t)NUSERS + 1) * BATCH * 2);
    int*    uptr   = (int*)carve(NUSERS * 4);
    int*    iptr   = (int*)carve(NITEMS * 4);
    int*    udeg   = (int*)carve(NUSERS * 4);
    int*    ideg   = (int*)carve(NITEMS * 4);
    int*    bcurU  = (int*)carve(NBUCKU * 4);
    int*    bcurI  = (int*)carve(NBUCKI * 4);
    int*    ucol   = (int*)carve(NEU * 4);
    int*    irow   = (int*)carve(NEI * 4);
    // staging aliases tauHall (dead until zero_pads + transpose_scale)
    int*    stU    = (int*)tauHall;
    int*    stI    = (int*)tauHall + NEU;
    (void)ws_size;

    float c[ORDER + 1];
    cheby_coeffs_host(c);
    Coeffs cf;
    float csum = 0.f;
    for (int k = 0; k <= ORDER; ++k) { cf.v[k] = c[k]; csum += c[k]; }

    // ---- CSR build: fixed-capacity buckets, padded rows ----
    init_bcur<<<(NBUCKU + 255) / 256, 256, 0, stream>>>(bcurU, bcurI);
    scatter1<<<S1_BLOCKS, 256, 0, stream>>>(row, col, bcurU, bcurI, stU, stI, nnz);
    scatter2<<<NBUCKU, 256, 0, stream>>>(bcurU, stU, uptr, udeg, ucol, NUSERS, CAPU, NITEMS);
    scatter2<<<NBUCKI, 256, 0, stream>>>(bcurI, stI, iptr, ideg, irow, NITEMS, CAPI, NUSERS);
    zero_pads<<<1, 256, 0, stream>>>(tauHall, (__half*)ybuf);

    // ---- tau0 (fp32 + fp16 slot 0) ----
    dim3 tb(32, 8);
    transpose_scale_k<<<dim3((NITEMS + 31) / 32, (BATCH + 31) / 32), tb, 0, stream>>>(
        signal, ideg, tauA, tauHall);

    const int ug = ((NUSERS / 2) * 64 + 255) / 256;   // user: 2 rows/wave
    const int ig = ((NITEMS / 4) * 64 + 255) / 256;   // item: 4 rows/wave

    // ---- k = 1 ----
    spmm_user<<<ug, 256, 0, stream>>>(uptr, udeg, ucol, (const Half4*)tauHall, ybuf);
    spmm_item_first<<<ig, 256, 0, stream>>>(iptr, ideg, irow, ybuf, tauA, tauB,
                                            (Half4*)(tauHall + SLOT));

    float* t0 = tauA;
    float* t1 = tauB;
    for (int k = 2; k <= ORDER; ++k) {
        spmm_user<<<ug, 256, 0, stream>>>(uptr, udeg, ucol,
                                          (const Half4*)(tauHall + (size_t)(k - 1) * SLOT), ybuf);
        spmm_item_k<<<ig, 256, 0, stream>>>(iptr, ideg, irow, ybuf, t1, t0,
                                            (Half4*)(tauHall + (size_t)k * SLOT));
        float* tmp = t0; t0 = t1; t1 = tmp;
    }

    // ---- d_out = sqrt(di) * sum_k c_k tauH_k, transposed ----
    transpose_out_k<<<dim3((BATCH + 31) / 32, (NITEMS + 31) / 32), tb, 0, stream>>>(
        tauHall, signal, ideg, csum, cf, (float*)d_out);
}